// Round 20
// baseline (492.488 us; speedup 1.0000x reference)
//
#include <hip/hip_runtime.h>
#include <hip/hip_fp8.h>
#include <math.h>

typedef unsigned short u16;
typedef unsigned char u8;
typedef short s16x8 __attribute__((ext_vector_type(8)));
typedef short s16x4 __attribute__((ext_vector_type(4)));
typedef unsigned int u32x4 __attribute__((ext_vector_type(4)));
typedef unsigned int u32x2 __attribute__((ext_vector_type(2)));
typedef __bf16 bf16x8 __attribute__((ext_vector_type(8)));
typedef float f32x4 __attribute__((ext_vector_type(4)));
typedef unsigned short u16x2 __attribute__((ext_vector_type(2)));

__device__ __forceinline__ float bf2f(u16 u) {
  unsigned x = ((unsigned)u) << 16;
  return __builtin_bit_cast(float, x);
}
__device__ __forceinline__ u16 f2bf(float f) {
  unsigned x = __builtin_bit_cast(unsigned, f);
  unsigned r = (x + 0x7FFFu + ((x >> 16) & 1u)) >> 16;
  return (u16)r;
}
__device__ __forceinline__ u8 f2e4(float f) {
  __hip_fp8_e4m3 q(f);
  return (u8)q.__x;
}
// packed f32x2 -> 2 fp8 bytes (hardware v_cvt_pk_fp8_f32 when available)
__device__ __forceinline__ unsigned cvt2e4(float a, float b) {
#if __has_builtin(__builtin_amdgcn_cvt_pk_fp8_f32)
  return (unsigned)__builtin_amdgcn_cvt_pk_fp8_f32(a, b, 0, false) & 0xFFFFu;
#else
  return (unsigned)f2e4(a) | ((unsigned)f2e4(b) << 8);
#endif
}

// ---- bf16 MFMA wrapper (signature-robust) ----
template <typename T>
__device__ __forceinline__ auto mfma_try(T a, T b, f32x4 c, int)
    -> decltype(__builtin_amdgcn_mfma_f32_16x16x32_bf16(a, b, c, 0, 0, 0)) {
  return __builtin_amdgcn_mfma_f32_16x16x32_bf16(a, b, c, 0, 0, 0);
}
template <typename T>
__device__ __forceinline__ f32x4 mfma_try(T a, T b, f32x4 c, long) {
  return __builtin_amdgcn_mfma_f32_16x16x32_bf16(
      __builtin_bit_cast(bf16x8, a), __builtin_bit_cast(bf16x8, b), c, 0, 0, 0);
}
__device__ __forceinline__ f32x4 mfma16x16x32(s16x8 a, s16x8 b, f32x4 c) {
  return mfma_try(a, b, c, 0);
}

// ---- fp8 MFMA: builtin operand type is 'long' (i64) on gfx950 ----
__device__ __forceinline__ f32x4 mfma8(long a, long b, f32x4 c) {
  return __builtin_amdgcn_mfma_f32_16x16x32_fp8_fp8(a, b, c, 0, 0, 0);
}

// ---- async global->LDS, 16B per lane ----
__device__ __forceinline__ void gload_lds16(const u16* g, u16* l) {
  __builtin_amdgcn_global_load_lds(
      (__attribute__((address_space(1))) void*)(u16*)g,
      (__attribute__((address_space(3))) void*)l, 16, 0, 0);
}

// ---------------- K0: pack weights (W1,W2 -> fp8x64 octets; fp_w -> bf16), rowmaps ----
__global__ __launch_bounds__(256) void pack_kernel(
    const float* __restrict__ w1, const float* __restrict__ w2,
    const float* __restrict__ fpw, const int* __restrict__ idx1,
    const int* __restrict__ idx2, u8* __restrict__ w1p8, u8* __restrict__ w2p8,
    u16* __restrict__ fpwp, int* __restrict__ rm1, int* __restrict__ rm2) {
  const int T1 = 589824;           // w1 (384x1536)
  const int T2 = T1 + 589824;      // w2 (1536x384)
  const int T3 = T2 + 147456;      // fp_w (384x384)
  const int T4 = T3 + 50176;       // rowmap1
  const int T5 = T4 + 50176;       // rowmap2
  int stride = gridDim.x * 256;
  for (int i = blockIdx.x * 256 + threadIdx.x; i < T5; i += stride) {
    if (i < T1) {
      int k = i / 1536, n = i - k * 1536;
      w1p8[((size_t)(k >> 3) * 1536 + n) * 8 + (k & 7)] = f2e4(w1[i] * 64.f);
    } else if (i < T2) {
      int t = i - T1;
      int k = t / 384, n = t - k * 384;
      w2p8[((size_t)(k >> 3) * 384 + n) * 8 + (k & 7)] = f2e4(w2[t] * 64.f);
    } else if (i < T3) {
      int t = i - T2;
      int k = t / 384, n = t - k * 384;
      fpwp[((size_t)(k >> 3) * 384 + n) * 8 + (k & 7)] = f2bf(fpw[t]);
    } else if (i < T4) {
      int g = i - T3;
      rm1[g] = (g / 392) * 784 + idx1[g];
    } else {
      int g = i - T4;
      rm2[g] = (g / 392) * 784 + idx2[g];
    }
  }
}

// ---------------- K1: depthwise 7x7 conv + bias -> t (B,N,C) bf16 ----------------
__global__ __launch_bounds__(256) void dwconv_kernel(
    const float* __restrict__ x, const float* __restrict__ dww,
    const float* __restrict__ dwb, u16* __restrict__ t) {
  __shared__ __align__(16) u16 plane[8 * 34 * 40];  // 21760 B
  int tid = threadIdx.x;
  int b = blockIdx.y, c0 = blockIdx.x * 8;
  int ch = tid & 7, row = tid >> 3;
  int c = c0 + ch;

  float wg[49];
#pragma unroll
  for (int k2 = 0; k2 < 49; ++k2) wg[k2] = dww[c * 49 + k2];
  float bias = dwb[c];

  for (int q = tid; q < 1360; q += 256) {
    s16x8 z = {0, 0, 0, 0, 0, 0, 0, 0};
    *(s16x8*)(&plane[q * 8]) = z;
  }
  __syncthreads();
  for (int q = tid; q < 1568; q += 256) {
    int cc = q / 196, seg = q - cc * 196;
    int i = seg / 7, j4 = seg - i * 7;
    const float4 v = *(const float4*)(x + ((size_t)(b * 384 + c0 + cc)) * 784 +
                                      i * 28 + j4 * 4);
    s16x4 p;
    p[0] = (short)f2bf(v.x);
    p[1] = (short)f2bf(v.y);
    p[2] = (short)f2bf(v.z);
    p[3] = (short)f2bf(v.w);
    *(s16x4*)(&plane[cc * 1360 + (3 + i) * 40 + 4 + j4 * 4]) = p;
  }
  __syncthreads();

  if (row < 28) {
    size_t obase = ((size_t)(b * 784 + row * 28)) * 384 + c;
#pragma unroll
    for (int ck = 0; ck < 4; ++ck) {
      float acc[8];
#pragma unroll
      for (int o = 0; o < 8; ++o) acc[o] = bias;
#pragma unroll
      for (int di = 0; di < 7; ++di) {
        const u16* base2 = &plane[ch * 1360 + (row + di) * 40 + ck * 8];
        u32x4 ga = *(const u32x4*)(base2);
        u32x4 gb = *(const u32x4*)(base2 + 8);
        unsigned dw[8] = {ga[0], ga[1], ga[2], ga[3],
                          gb[0], gb[1], gb[2], gb[3]};
        float v[16];
#pragma unroll
        for (int tt = 0; tt < 16; ++tt) {
          unsigned d = dw[tt >> 1];
          v[tt] = (tt & 1) ? __builtin_bit_cast(float, d & 0xFFFF0000u)
                           : __builtin_bit_cast(float, d << 16);
        }
#pragma unroll
        for (int o = 0; o < 8; ++o)
#pragma unroll
          for (int dj = 0; dj < 7; ++dj)
            acc[o] += v[o + dj + 1] * wg[di * 7 + dj];
      }
      int lim = (ck == 3) ? 4 : 8;
#pragma unroll
      for (int o = 0; o < 8; ++o)
        if (o < lim) t[obase + (size_t)(ck * 8 + o) * 384] = f2bf(acc[o]);
    }
  }
}

// ---------------- K2: gather + LayerNorm -> A1 (fp8), A2 (bf16) ----------------
__global__ __launch_bounds__(256) void gatherln_kernel(
    const u16* __restrict__ t, const int* __restrict__ idx1,
    const int* __restrict__ idx2, const float* __restrict__ nw1,
    const float* __restrict__ nb1, const float* __restrict__ nw2,
    const float* __restrict__ nb2, u8* __restrict__ A1f,
    u16* __restrict__ A2) {
  int wid = threadIdx.x >> 6, lane = threadIdx.x & 63;
  int g = blockIdx.x * 4 + wid;
  bool is1 = g < 50176;
  int gg = is1 ? g : g - 50176;
  const int* idx = is1 ? idx1 : idx2;
  int b = gg / 392;
  int jj = gg - b * 392;
  int ntok = idx[b * 392 + jj];
  const u16* src = t + ((size_t)(b * 784 + ntok)) * 384 + lane * 6;
  float v[6];
  u16x2 u0 = *(const u16x2*)(src);
  u16x2 u1 = *(const u16x2*)(src + 2);
  u16x2 u2 = *(const u16x2*)(src + 4);
  v[0] = bf2f(u0[0]); v[1] = bf2f(u0[1]);
  v[2] = bf2f(u1[0]); v[3] = bf2f(u1[1]);
  v[4] = bf2f(u2[0]); v[5] = bf2f(u2[1]);
  float s = 0.f, q = 0.f;
#pragma unroll
  for (int e = 0; e < 6; ++e) { s += v[e]; q += v[e] * v[e]; }
#pragma unroll
  for (int off = 32; off >= 1; off >>= 1) {
    s += __shfl_xor(s, off);
    q += __shfl_xor(q, off);
  }
  float mu = s * (1.f / 384.f);
  float var = q * (1.f / 384.f) - mu * mu;
  float rs = rsqrtf(var + 1e-6f);
  const float* nw = is1 ? nw1 : nw2;
  const float* nb = is1 ? nb1 : nb2;
  int k0 = lane * 6;
  float o[6];
#pragma unroll
  for (int e = 0; e < 6; ++e)
    o[e] = (v[e] - mu) * rs * nw[k0 + e] + nb[k0 + e];
  if (is1) {
    u8* dst = A1f + (size_t)gg * 384 + lane * 6;
#pragma unroll
    for (int e = 0; e < 6; e += 2) *(u16*)(dst + e) = (u16)cvt2e4(o[e], o[e + 1]);
  } else {
    unsigned* dst = (unsigned*)(A2 + (size_t)gg * 384 + lane * 6);
#pragma unroll
    for (int e = 0; e < 3; ++e)
      dst[e] = (unsigned)f2bf(o[2 * e]) | ((unsigned)f2bf(o[2 * e + 1]) << 16);
  }
}

// ---------------- K3+K4 FUSED (fp8): U[rm1] = (gelu(A1@W1+b1)@W2 + b2)*gamma ----
// BM=16, 256 thr (4 waves). fp8 e4m3 datapath (W pre-scaled x64).
// Hard-sigmoid gelu. acc regs 36/thread -> total ~96 regs => 4-5 waves/SIMD
// (R19 at BM=32 was 136 regs -> 3 waves, occ 34%). W L2 reads 2x vs BM=32
// (~3.7 GB, under per-XCD L2 BW). Alds 6 KB; Plds dbuf 2x3 KB; 1 barrier/chunk.
__global__ __launch_bounds__(256, 4) void fused_mlp_kernel(
    const u8* __restrict__ A, const u8* __restrict__ w1p8,
    const u8* __restrict__ w2p8, const float* __restrict__ b1,
    const float* __restrict__ b2, const float* __restrict__ gamma,
    const int* __restrict__ rm, u16* __restrict__ U) {
  __shared__ __align__(16) u8 Alds[48 * 16 * 8];     // 6144 B
  __shared__ __align__(16) u8 Plds[2][24 * 16 * 8];  // 2 x 3072 B
  int tid = threadIdx.x;
  int wid = tid >> 6, lane = tid & 63;
  int kgl = lane >> 4, rl = lane & 15;
  int cl = lane & 15, rg = (lane >> 4) * 4;
  int m_base = blockIdx.x * 16;

  // stage A-tile (16 rows x 384 fp8 = 6KB): 384 16B-chunks, 24 per row
#pragma unroll
  for (int it = 0; it < 2; ++it) {
    int c16 = it * 256 + tid;
    if (c16 < 384) {
      int row = c16 / 24, cc = c16 - row * 24;
      u32x4 v = *(const u32x4*)(A + (size_t)(m_base + row) * 384 + cc * 16);
      u32x2 lo = {v[0], v[1]}, hi = {v[2], v[3]};
      *(u32x2*)&Alds[((2 * cc) * 16 + row) * 8] = lo;
      *(u32x2*)&Alds[((2 * cc + 1) * 16 + row) * 8] = hi;
    }
  }

  const f32x4 vzero = {0.f, 0.f, 0.f, 0.f};
  f32x4 accB[6];
#pragma unroll
  for (int j = 0; j < 6; ++j) accB[j] = vzero;

  __syncthreads();

#pragma unroll 1
  for (int c = 0; c < 8; ++c) {
    u8* Pl = Plds[c & 1];
    // ---- phase A: accA = A(16x384) @ W1[:, c*192 + wid*48 .. +48] ----
    f32x4 accA[3];
#pragma unroll
    for (int j = 0; j < 3; ++j) accA[j] = vzero;
#pragma unroll
    for (int ks = 0; ks < 12; ++ks) {
      long af = *(const long*)&Alds[((ks * 4 + kgl) * 16 + rl) * 8];
      long bw[3];
#pragma unroll
      for (int j = 0; j < 3; ++j) {
        int col = c * 192 + wid * 48 + j * 16 + rl;
        bw[j] = *(const long*)(w1p8 + ((size_t)(ks * 4 + kgl) * 1536 + col) * 8);
      }
      __builtin_amdgcn_s_setprio(1);
#pragma unroll
      for (int j = 0; j < 3; ++j) accA[j] = mfma8(af, bw[j], accA[j]);
      __builtin_amdgcn_s_setprio(0);
    }
    // bias + hard-sigmoid gelu -> Pl fp8 (unscale W1's x64)
    float b1v[3];
#pragma unroll
    for (int j = 0; j < 3; ++j) b1v[j] = b1[c * 192 + wid * 48 + j * 16 + cl];
#pragma unroll
    for (int j = 0; j < 3; ++j) {
      int col = wid * 48 + j * 16 + cl;
      float g2[4];
#pragma unroll
      for (int reg = 0; reg < 4; ++reg) {
        float v = accA[j][reg] * 0.015625f + b1v[j];
        g2[reg] = v * fminf(fmaxf(0.4255f * v + 0.5f, 0.f), 1.f);
      }
      unsigned p01 = cvt2e4(g2[0], g2[1]);
      unsigned p23 = cvt2e4(g2[2], g2[3]);
      int base = ((col >> 3) * 16 + rg) * 8 + (col & 7);
      Pl[base] = (u8)p01;
      Pl[base + 8] = (u8)(p01 >> 8);
      Pl[base + 16] = (u8)p23;
      Pl[base + 24] = (u8)(p23 >> 8);
    }
    __syncthreads();
    // ---- phase B: accB += P(16x192) @ W2[c*192.., wid*96 .. +96] ----
#pragma unroll
    for (int ks = 0; ks < 6; ++ks) {
      long ap = *(const long*)&Pl[((ks * 4 + kgl) * 16 + rl) * 8];
      long bw2[6];
#pragma unroll
      for (int j = 0; j < 6; ++j) {
        int col = wid * 96 + j * 16 + rl;
        int ko2 = c * 24 + ks * 4 + kgl;
        bw2[j] = *(const long*)(w2p8 + ((size_t)ko2 * 384 + col) * 8);
      }
      __builtin_amdgcn_s_setprio(1);
#pragma unroll
      for (int j = 0; j < 6; ++j) accB[j] = mfma8(ap, bw2[j], accB[j]);
      __builtin_amdgcn_s_setprio(0);
    }
    // no second barrier: next chunk writes the OTHER P buffer
  }

  // epilogue: U[rm[m]*384 + col] = bf16((accB/64 + b2[col]) * gamma[col])
#pragma unroll
  for (int reg = 0; reg < 4; ++reg) {
    int m = m_base + rg + reg;
    size_t rowoff = (size_t)rm[m] * 384;
#pragma unroll
    for (int j = 0; j < 6; ++j) {
      int col = wid * 96 + j * 16 + cl;
      float v = (accB[j][reg] * 0.015625f + b2[col]) * gamma[col];
      U[rowoff + col] = f2bf(v);
    }
  }
}

// ---------------- K5: bf16 MFMA GEMM, 128x128 tile, 4 waves (R5 dbuf) ----
__global__ __launch_bounds__(256) void gemm_kernel(
    const u16* __restrict__ A, const u16* __restrict__ Wp,
    const float* __restrict__ bias, const float* __restrict__ scale,
    const int* __restrict__ rowmap, u16* __restrict__ out, int N, int K,
    int gx) {
  __shared__ __align__(16) u16 As[2][4096];
  __shared__ __align__(16) u16 Bs[2][4096];
  int tid = threadIdx.x;
  int wid = tid >> 6, lane = tid & 63;
  int wm = wid >> 1, wn = wid & 1;
  int nwg = gridDim.x;
  int bid = blockIdx.x;
  int wgid = (bid & 7) * (nwg >> 3) + (bid >> 3);
  int by = wgid / gx, bx = wgid - by * gx;
  int m_base = by * 128, n_base = bx * 128;
  const f32x4 vzero = {0.f, 0.f, 0.f, 0.f};
  f32x4 acc[4][4];
#pragma unroll
  for (int i = 0; i < 4; ++i)
#pragma unroll
    for (int j = 0; j < 4; ++j) acc[i][j] = vzero;
  int nk = K >> 5;

  auto stage = [&](int buf, int kt) {
#pragma unroll
    for (int it = 0; it < 2; ++it) {
      int p = wid * 128 + it * 64 + lane;
      int kg = p >> 7, row = p & 127;
      const u16* ga = A + (size_t)(m_base + row) * K + (kt << 5) + (kg << 3);
      gload_lds16(ga, &As[buf][(wid * 128 + it * 64) * 8]);
    }
#pragma unroll
    for (int it = 0; it < 2; ++it) {
      int p = wid * 128 + it * 64 + lane;
      int kg = p >> 7, col = p & 127;
      const u16* gb = Wp + ((size_t)((kt << 2) + kg) * N + n_base + col) * 8;
      gload_lds16(gb, &Bs[buf][(wid * 128 + it * 64) * 8]);
    }
  };

  stage(0, 0);
  __syncthreads();
  int cur = 0;
  for (int kt = 0; kt < nk; ++kt) {
    if (kt + 1 < nk) stage(cur ^ 1, kt + 1);
    int kg = lane >> 4, r = lane & 15;
    s16x8 af[4], bfr[4];
#pragma unroll
    for (int i = 0; i < 4; ++i)
      af[i] = *(const s16x8*)(&As[cur][(kg * 128 + wm * 64 + i * 16 + r) * 8]);
#pragma unroll
    for (int j = 0; j < 4; ++j)
      bfr[j] = *(const s16x8*)(&Bs[cur][(kg * 128 + wn * 64 + j * 16 + r) * 8]);
#pragma unroll
    for (int i = 0; i < 4; ++i)
#pragma unroll
      for (int j = 0; j < 4; ++j)
        acc[i][j] = mfma16x16x32(af[i], bfr[j], acc[i][j]);
    __syncthreads();
    cur ^= 1;
  }
  int cl = lane & 15;
  int rg = (lane >> 4) * 4;
#pragma unroll
  for (int i = 0; i < 4; ++i) {
#pragma unroll
    for (int reg = 0; reg < 4; ++reg) {
      int m = m_base + wm * 64 + i * 16 + rg + reg;
      size_t rowoff = (size_t)rowmap[m] * 384;
#pragma unroll
      for (int j = 0; j < 4; ++j) {
        int col = n_base + wn * 64 + j * 16 + cl;
        float v = acc[i][j][reg];
        v = (v + bias[col]) * scale[col];
        out[rowoff + col] = f2bf(v);
      }
    }
  }
}

// ---------------- K6: un-transpose (B,N,C)->(B,C,N) + residual add ----------------
// Vectorized: 32c x 128n tile; U reads s16x4 (8B/lane), x/out float4 IO.
__global__ __launch_bounds__(256) void unscatter_add_kernel(
    const u16* __restrict__ U, const float* __restrict__ x,
    float* __restrict__ out) {
  __shared__ float tile[32][129];
  int b = blockIdx.y;
  int ct = blockIdx.x % 12, nt = blockIdx.x / 12;
  int c0 = ct * 32, n0 = nt * 128;
  int tid = threadIdx.x;
#pragma unroll
  for (int it = 0; it < 4; ++it) {
    int q = tid + it * 256;
    int nl = q >> 3, cg = (q & 7) * 4;
    int n = n0 + nl;
    if (n < 784) {
      s16x4 v = *(const s16x4*)(U + ((size_t)(b * 784 + n)) * 384 + c0 + cg);
      tile[cg + 0][nl] = bf2f((u16)v[0]);
      tile[cg + 1][nl] = bf2f((u16)v[1]);
      tile[cg + 2][nl] = bf2f((u16)v[2]);
      tile[cg + 3][nl] = bf2f((u16)v[3]);
    }
  }
  __syncthreads();
#pragma unroll
  for (int it = 0; it < 4; ++it) {
    int q = tid + it * 256;
    int c = q >> 5, nf = (q & 31) * 4;
    int n = n0 + nf;
    if (n + 3 < 784) {
      size_t o = ((size_t)(b * 384 + c0 + c)) * 784 + n;
      float4 xv = *(const float4*)(x + o);
      float4 r;
      r.x = xv.x + tile[c][nf + 0];
      r.y = xv.y + tile[c][nf + 1];
      r.z = xv.z + tile[c][nf + 2];
      r.w = xv.w + tile[c][nf + 3];
      *(float4*)(out + o) = r;
    }
  }
}

extern "C" void kernel_launch(void* const* d_in, const int* in_sizes, int n_in,
                              void* d_out, int out_size, void* d_ws,
                              size_t ws_size, hipStream_t stream) {
  const float* x = (const float*)d_in[0];
  const int* idx1 = (const int*)d_in[1];
  const int* idx2 = (const int*)d_in[2];
  const float* dww = (const float*)d_in[3];
  const float* dwb = (const float*)d_in[4];
  const float* nw = (const float*)d_in[5];
  const float* nb = (const float*)d_in[6];
  const float* w1 = (const float*)d_in[7];
  const float* b1 = (const float*)d_in[8];
  const float* w2 = (const float*)d_in[9];
  const float* b2 = (const float*)d_in[10];
  const float* gamma = (const float*)d_in[11];
  const float* fnw = (const float*)d_in[12];
  const float* fnb = (const float*)d_in[13];
  const float* fpw = (const float*)d_in[14];
  const float* fpb = (const float*)d_in[15];
  const float* fpg = (const float*)d_in[16];

  char* ws = (char*)d_ws;
  u16* t = (u16*)(ws);                     //  77,070,336 B (100352x384 bf16)
  u8* A1f = (u8*)(ws + 77070336);          //  19,267,584 B (50176x384 fp8)
  u16* A2 = (u16*)(ws + 96337920);         //  38,535,168 B (50176x384 bf16)
  u16* U = (u16*)(ws + 134873088);         //  77,070,336 B (100352x384 bf16)
  u8* w1p8 = (u8*)(ws + 211943424);        //     589,824 B
  u8* w2p8 = (u8*)(ws + 212533248);        //     589,824 B
  u16* fpwp = (u16*)(ws + 213123072);      //     294,912 B
  int* rm1 = (int*)(ws + 213417984);       //     200,704 B
  int* rm2 = (int*)(ws + 213618688);       //     200,704 B
  (void)ws_size; (void)in_sizes; (void)n_in; (void)out_size;

  pack_kernel<<<1024, 256, 0, stream>>>(w1, w2, fpw, idx1, idx2, w1p8, w2p8,
                                        fpwp, rm1, rm2);
  dwconv_kernel<<<dim3(48, 128), 256, 0, stream>>>(x, dww, dwb, t);
  gatherln_kernel<<<25088, 256, 0, stream>>>(t, idx1, idx2, nw, nb, fnw, fnb,
                                             A1f, A2);
  fused_mlp_kernel<<<3136, 256, 0, stream>>>(A1f, w1p8, w2p8, b1, b2, gamma,
                                             rm1, U);
  gemm_kernel<<<1176, 256, 0, stream>>>(A2, fpwp, fpb, fpg, rm2, U, 384, 384,
                                        3);
  unscatter_add_kernel<<<dim3(84, 128), 256, 0, stream>>>(U, x,
                                                          (float*)d_out);
}

// Round 21
// 393.828 us; speedup vs baseline: 1.2505x; 1.2505x over previous
//
#include <hip/hip_runtime.h>
#include <hip/hip_fp8.h>
#include <math.h>

typedef unsigned short u16;
typedef unsigned char u8;
typedef short s16x8 __attribute__((ext_vector_type(8)));
typedef short s16x4 __attribute__((ext_vector_type(4)));
typedef unsigned int u32x4 __attribute__((ext_vector_type(4)));
typedef unsigned int u32x2 __attribute__((ext_vector_type(2)));
typedef __bf16 bf16x8 __attribute__((ext_vector_type(8)));
typedef float f32x4 __attribute__((ext_vector_type(4)));
typedef unsigned short u16x2 __attribute__((ext_vector_type(2)));

__device__ __forceinline__ float bf2f(u16 u) {
  unsigned x = ((unsigned)u) << 16;
  return __builtin_bit_cast(float, x);
}
__device__ __forceinline__ u16 f2bf(float f) {
  unsigned x = __builtin_bit_cast(unsigned, f);
  unsigned r = (x + 0x7FFFu + ((x >> 16) & 1u)) >> 16;
  return (u16)r;
}
__device__ __forceinline__ u8 f2e4(float f) {
  __hip_fp8_e4m3 q(f);
  return (u8)q.__x;
}
// packed f32x2 -> 2 fp8 bytes (hardware v_cvt_pk_fp8_f32 when available)
__device__ __forceinline__ unsigned cvt2e4(float a, float b) {
#if __has_builtin(__builtin_amdgcn_cvt_pk_fp8_f32)
  return (unsigned)__builtin_amdgcn_cvt_pk_fp8_f32(a, b, 0, false) & 0xFFFFu;
#else
  return (unsigned)f2e4(a) | ((unsigned)f2e4(b) << 8);
#endif
}

// ---- fp8 MFMA: builtin operand type is 'long' (i64) on gfx950 ----
__device__ __forceinline__ f32x4 mfma8(long a, long b, f32x4 c) {
  return __builtin_amdgcn_mfma_f32_16x16x32_fp8_fp8(a, b, c, 0, 0, 0);
}

// ---- async global->LDS, 16B per lane ----
__device__ __forceinline__ void gload_lds16(const u16* g, u16* l) {
  __builtin_amdgcn_global_load_lds(
      (__attribute__((address_space(1))) void*)(u16*)g,
      (__attribute__((address_space(3))) void*)l, 16, 0, 0);
}

// ---------------- K0: pack weights (W1,W2,fp_w -> fp8x64 octets), rowmaps ----
__global__ __launch_bounds__(256) void pack_kernel(
    const float* __restrict__ w1, const float* __restrict__ w2,
    const float* __restrict__ fpw, const int* __restrict__ idx1,
    const int* __restrict__ idx2, u8* __restrict__ w1p8, u8* __restrict__ w2p8,
    u8* __restrict__ fpw8, int* __restrict__ rm1, int* __restrict__ rm2) {
  const int T1 = 589824;           // w1 (384x1536)
  const int T2 = T1 + 589824;      // w2 (1536x384)
  const int T3 = T2 + 147456;      // fp_w (384x384)
  const int T4 = T3 + 50176;       // rowmap1
  const int T5 = T4 + 50176;       // rowmap2
  int stride = gridDim.x * 256;
  for (int i = blockIdx.x * 256 + threadIdx.x; i < T5; i += stride) {
    if (i < T1) {
      int k = i / 1536, n = i - k * 1536;
      w1p8[((size_t)(k >> 3) * 1536 + n) * 8 + (k & 7)] = f2e4(w1[i] * 64.f);
    } else if (i < T2) {
      int t = i - T1;
      int k = t / 384, n = t - k * 384;
      w2p8[((size_t)(k >> 3) * 384 + n) * 8 + (k & 7)] = f2e4(w2[t] * 64.f);
    } else if (i < T3) {
      int t = i - T2;
      int k = t / 384, n = t - k * 384;
      fpw8[((size_t)(k >> 3) * 384 + n) * 8 + (k & 7)] = f2e4(fpw[t] * 64.f);
    } else if (i < T4) {
      int g = i - T3;
      rm1[g] = (g / 392) * 784 + idx1[g];
    } else {
      int g = i - T4;
      rm2[g] = (g / 392) * 784 + idx2[g];
    }
  }
}

// ---------------- K1: depthwise 7x7 conv + bias -> t (B,N,C) bf16 ----------------
__global__ __launch_bounds__(256) void dwconv_kernel(
    const float* __restrict__ x, const float* __restrict__ dww,
    const float* __restrict__ dwb, u16* __restrict__ t) {
  __shared__ __align__(16) u16 plane[8 * 34 * 40];  // 21760 B
  int tid = threadIdx.x;
  int b = blockIdx.y, c0 = blockIdx.x * 8;
  int ch = tid & 7, row = tid >> 3;
  int c = c0 + ch;

  float wg[49];
#pragma unroll
  for (int k2 = 0; k2 < 49; ++k2) wg[k2] = dww[c * 49 + k2];
  float bias = dwb[c];

  for (int q = tid; q < 1360; q += 256) {
    s16x8 z = {0, 0, 0, 0, 0, 0, 0, 0};
    *(s16x8*)(&plane[q * 8]) = z;
  }
  __syncthreads();
  for (int q = tid; q < 1568; q += 256) {
    int cc = q / 196, seg = q - cc * 196;
    int i = seg / 7, j4 = seg - i * 7;
    const float4 v = *(const float4*)(x + ((size_t)(b * 384 + c0 + cc)) * 784 +
                                      i * 28 + j4 * 4);
    s16x4 p;
    p[0] = (short)f2bf(v.x);
    p[1] = (short)f2bf(v.y);
    p[2] = (short)f2bf(v.z);
    p[3] = (short)f2bf(v.w);
    *(s16x4*)(&plane[cc * 1360 + (3 + i) * 40 + 4 + j4 * 4]) = p;
  }
  __syncthreads();

  if (row < 28) {
    size_t obase = ((size_t)(b * 784 + row * 28)) * 384 + c;
#pragma unroll
    for (int ck = 0; ck < 4; ++ck) {
      float acc[8];
#pragma unroll
      for (int o = 0; o < 8; ++o) acc[o] = bias;
#pragma unroll
      for (int di = 0; di < 7; ++di) {
        const u16* base2 = &plane[ch * 1360 + (row + di) * 40 + ck * 8];
        u32x4 ga = *(const u32x4*)(base2);
        u32x4 gb = *(const u32x4*)(base2 + 8);
        unsigned dw[8] = {ga[0], ga[1], ga[2], ga[3],
                          gb[0], gb[1], gb[2], gb[3]};
        float v[16];
#pragma unroll
        for (int tt = 0; tt < 16; ++tt) {
          unsigned d = dw[tt >> 1];
          v[tt] = (tt & 1) ? __builtin_bit_cast(float, d & 0xFFFF0000u)
                           : __builtin_bit_cast(float, d << 16);
        }
#pragma unroll
        for (int o = 0; o < 8; ++o)
#pragma unroll
          for (int dj = 0; dj < 7; ++dj)
            acc[o] += v[o + dj + 1] * wg[di * 7 + dj];
      }
      int lim = (ck == 3) ? 4 : 8;
#pragma unroll
      for (int o = 0; o < 8; ++o)
        if (o < lim) t[obase + (size_t)(ck * 8 + o) * 384] = f2bf(acc[o]);
    }
  }
}

// ---------------- K2: gather + LayerNorm -> A1f, A2f (both fp8) ----------------
__global__ __launch_bounds__(256) void gatherln_kernel(
    const u16* __restrict__ t, const int* __restrict__ idx1,
    const int* __restrict__ idx2, const float* __restrict__ nw1,
    const float* __restrict__ nb1, const float* __restrict__ nw2,
    const float* __restrict__ nb2, u8* __restrict__ A1f,
    u8* __restrict__ A2f) {
  int wid = threadIdx.x >> 6, lane = threadIdx.x & 63;
  int g = blockIdx.x * 4 + wid;
  bool is1 = g < 50176;
  int gg = is1 ? g : g - 50176;
  const int* idx = is1 ? idx1 : idx2;
  int b = gg / 392;
  int jj = gg - b * 392;
  int ntok = idx[b * 392 + jj];
  const u16* src = t + ((size_t)(b * 784 + ntok)) * 384 + lane * 6;
  float v[6];
  u16x2 u0 = *(const u16x2*)(src);
  u16x2 u1 = *(const u16x2*)(src + 2);
  u16x2 u2 = *(const u16x2*)(src + 4);
  v[0] = bf2f(u0[0]); v[1] = bf2f(u0[1]);
  v[2] = bf2f(u1[0]); v[3] = bf2f(u1[1]);
  v[4] = bf2f(u2[0]); v[5] = bf2f(u2[1]);
  float s = 0.f, q = 0.f;
#pragma unroll
  for (int e = 0; e < 6; ++e) { s += v[e]; q += v[e] * v[e]; }
#pragma unroll
  for (int off = 32; off >= 1; off >>= 1) {
    s += __shfl_xor(s, off);
    q += __shfl_xor(q, off);
  }
  float mu = s * (1.f / 384.f);
  float var = q * (1.f / 384.f) - mu * mu;
  float rs = rsqrtf(var + 1e-6f);
  const float* nw = is1 ? nw1 : nw2;
  const float* nb = is1 ? nb1 : nb2;
  int k0 = lane * 6;
  float o[6];
#pragma unroll
  for (int e = 0; e < 6; ++e)
    o[e] = (v[e] - mu) * rs * nw[k0 + e] + nb[k0 + e];
  u8* dst = (is1 ? A1f : A2f) + (size_t)gg * 384 + lane * 6;
#pragma unroll
  for (int e = 0; e < 6; e += 2) *(u16*)(dst + e) = (u16)cvt2e4(o[e], o[e + 1]);
}

// ---------------- K3+K4 FUSED (fp8): U[rm1] = (gelu(A1@W1+b1)@W2 + b2)*gamma ----
// BM=32, 256 thr (4 waves). fp8 e4m3 datapath (W pre-scaled x64).
// Hard-sigmoid gelu. R19 config (best: 154us, occ 34%, MfmaUtil 33%).
__global__ __launch_bounds__(256, 4) void fused_mlp_kernel(
    const u8* __restrict__ A, const u8* __restrict__ w1p8,
    const u8* __restrict__ w2p8, const float* __restrict__ b1,
    const float* __restrict__ b2, const float* __restrict__ gamma,
    const int* __restrict__ rm, u16* __restrict__ U) {
  __shared__ __align__(16) u8 Alds[48 * 32 * 8];     // 12288 B
  __shared__ __align__(16) u8 Plds[2][24 * 32 * 8];  // 2 x 6144 B
  int tid = threadIdx.x;
  int wid = tid >> 6, lane = tid & 63;
  int kgl = lane >> 4, rl = lane & 15;
  int cl = lane & 15, rg = (lane >> 4) * 4;
  int m_base = blockIdx.x * 32;

  // stage A-tile (32 rows x 384 fp8 = 12KB)
#pragma unroll
  for (int it = 0; it < 3; ++it) {
    int c16 = it * 256 + tid;      // 16B chunk id, 24 per row (768 total)
    int row = c16 / 24, cc = c16 - row * 24;
    u32x4 v = *(const u32x4*)(A + (size_t)(m_base + row) * 384 + cc * 16);
    u32x2 lo = {v[0], v[1]}, hi = {v[2], v[3]};
    *(u32x2*)&Alds[((2 * cc) * 32 + row) * 8] = lo;
    *(u32x2*)&Alds[((2 * cc + 1) * 32 + row) * 8] = hi;
  }

  const f32x4 vzero = {0.f, 0.f, 0.f, 0.f};
  f32x4 accB[2][6];
#pragma unroll
  for (int i = 0; i < 2; ++i)
#pragma unroll
    for (int j = 0; j < 6; ++j) accB[i][j] = vzero;

  __syncthreads();

#pragma unroll 1
  for (int c = 0; c < 8; ++c) {
    u8* Pl = Plds[c & 1];
    // ---- phase A: accA = A(32x384) @ W1[:, c*192 + wid*48 .. +48] ----
    f32x4 accA[2][3];
#pragma unroll
    for (int i = 0; i < 2; ++i)
#pragma unroll
      for (int j = 0; j < 3; ++j) accA[i][j] = vzero;
#pragma unroll
    for (int ks = 0; ks < 12; ++ks) {
      long af[2], bw[3];
#pragma unroll
      for (int i = 0; i < 2; ++i)
        af[i] = *(const long*)&Alds[((ks * 4 + kgl) * 32 + i * 16 + rl) * 8];
#pragma unroll
      for (int j = 0; j < 3; ++j) {
        int col = c * 192 + wid * 48 + j * 16 + rl;
        bw[j] = *(const long*)(w1p8 + ((size_t)(ks * 4 + kgl) * 1536 + col) * 8);
      }
      __builtin_amdgcn_s_setprio(1);
#pragma unroll
      for (int i = 0; i < 2; ++i)
#pragma unroll
        for (int j = 0; j < 3; ++j)
          accA[i][j] = mfma8(af[i], bw[j], accA[i][j]);
      __builtin_amdgcn_s_setprio(0);
    }
    // bias + hard-sigmoid gelu -> Pl fp8 (unscale W1's x64)
    float b1v[3];
#pragma unroll
    for (int j = 0; j < 3; ++j) b1v[j] = b1[c * 192 + wid * 48 + j * 16 + cl];
#pragma unroll
    for (int i = 0; i < 2; ++i)
#pragma unroll
      for (int j = 0; j < 3; ++j) {
        int col = wid * 48 + j * 16 + cl;
        float g2[4];
#pragma unroll
        for (int reg = 0; reg < 4; ++reg) {
          float v = accA[i][j][reg] * 0.015625f + b1v[j];
          g2[reg] = v * fminf(fmaxf(0.4255f * v + 0.5f, 0.f), 1.f);
        }
        unsigned p01 = cvt2e4(g2[0], g2[1]);
        unsigned p23 = cvt2e4(g2[2], g2[3]);
        int base = ((col >> 3) * 32 + i * 16 + rg) * 8 + (col & 7);
        Pl[base] = (u8)p01;
        Pl[base + 8] = (u8)(p01 >> 8);
        Pl[base + 16] = (u8)p23;
        Pl[base + 24] = (u8)(p23 >> 8);
      }
    __syncthreads();
    // ---- phase B: accB += P(32x192) @ W2[c*192.., wid*96 .. +96] ----
#pragma unroll
    for (int ks = 0; ks < 6; ++ks) {
      long ap[2], bw2[6];
#pragma unroll
      for (int i = 0; i < 2; ++i)
        ap[i] = *(const long*)&Pl[((ks * 4 + kgl) * 32 + i * 16 + rl) * 8];
#pragma unroll
      for (int j = 0; j < 6; ++j) {
        int col = wid * 96 + j * 16 + rl;
        int ko2 = c * 24 + ks * 4 + kgl;
        bw2[j] = *(const long*)(w2p8 + ((size_t)ko2 * 384 + col) * 8);
      }
      __builtin_amdgcn_s_setprio(1);
#pragma unroll
      for (int i = 0; i < 2; ++i)
#pragma unroll
        for (int j = 0; j < 6; ++j)
          accB[i][j] = mfma8(ap[i], bw2[j], accB[i][j]);
      __builtin_amdgcn_s_setprio(0);
    }
    // no second barrier: next chunk writes the OTHER P buffer
  }

  // epilogue: U[rm[m]*384 + col] = bf16((accB/64 + b2[col]) * gamma[col])
#pragma unroll
  for (int i = 0; i < 2; ++i) {
#pragma unroll
    for (int reg = 0; reg < 4; ++reg) {
      int m = m_base + i * 16 + rg + reg;
      size_t rowoff = (size_t)rm[m] * 384;
#pragma unroll
      for (int j = 0; j < 6; ++j) {
        int col = wid * 96 + j * 16 + cl;
        float v = (accB[i][j][reg] * 0.015625f + b2[col]) * gamma[col];
        U[rowoff + col] = f2bf(v);
      }
    }
  }
}

// ---------------- K5 (fp8): U[rm2] = (A2f @ fp_w + fp_b) * fp_gamma ----------
// Copy of fused phase A skeleton: BM=32, 4 waves x 96 cols, acc[2][6].
__global__ __launch_bounds__(256, 4) void gemm5_kernel(
    const u8* __restrict__ A, const u8* __restrict__ wp8,
    const float* __restrict__ bias, const float* __restrict__ scale,
    const int* __restrict__ rm, u16* __restrict__ U) {
  __shared__ __align__(16) u8 Alds[48 * 32 * 8];  // 12288 B
  int tid = threadIdx.x;
  int wid = tid >> 6, lane = tid & 63;
  int kgl = lane >> 4, rl = lane & 15;
  int cl = lane & 15, rg = (lane >> 4) * 4;
  int m_base = blockIdx.x * 32;

#pragma unroll
  for (int it = 0; it < 3; ++it) {
    int c16 = it * 256 + tid;
    int row = c16 / 24, cc = c16 - row * 24;
    u32x4 v = *(const u32x4*)(A + (size_t)(m_base + row) * 384 + cc * 16);
    u32x2 lo = {v[0], v[1]}, hi = {v[2], v[3]};
    *(u32x2*)&Alds[((2 * cc) * 32 + row) * 8] = lo;
    *(u32x2*)&Alds[((2 * cc + 1) * 32 + row) * 8] = hi;
  }

  const f32x4 vzero = {0.f, 0.f, 0.f, 0.f};
  f32x4 acc[2][6];
#pragma unroll
  for (int i = 0; i < 2; ++i)
#pragma unroll
    for (int j = 0; j < 6; ++j) acc[i][j] = vzero;

  __syncthreads();

#pragma unroll
  for (int ks = 0; ks < 12; ++ks) {
    long af[2], bw[6];
#pragma unroll
    for (int i = 0; i < 2; ++i)
      af[i] = *(const long*)&Alds[((ks * 4 + kgl) * 32 + i * 16 + rl) * 8];
#pragma unroll
    for (int j = 0; j < 6; ++j) {
      int col = wid * 96 + j * 16 + rl;
      bw[j] = *(const long*)(wp8 + ((size_t)(ks * 4 + kgl) * 384 + col) * 8);
    }
    __builtin_amdgcn_s_setprio(1);
#pragma unroll
    for (int i = 0; i < 2; ++i)
#pragma unroll
      for (int j = 0; j < 6; ++j)
        acc[i][j] = mfma8(af[i], bw[j], acc[i][j]);
    __builtin_amdgcn_s_setprio(0);
  }

#pragma unroll
  for (int i = 0; i < 2; ++i) {
#pragma unroll
    for (int reg = 0; reg < 4; ++reg) {
      int m = m_base + i * 16 + rg + reg;
      size_t rowoff = (size_t)rm[m] * 384;
#pragma unroll
      for (int j = 0; j < 6; ++j) {
        int col = wid * 96 + j * 16 + cl;
        float v = (acc[i][j][reg] * 0.015625f + bias[col]) * scale[col];
        U[rowoff + col] = f2bf(v);
      }
    }
  }
}

// ---------------- K6: un-transpose (B,N,C)->(B,C,N) + residual add ----------------
__global__ __launch_bounds__(256) void unscatter_add_kernel(
    const u16* __restrict__ U, const float* __restrict__ x,
    float* __restrict__ out) {
  __shared__ float tile[32][129];
  int b = blockIdx.y;
  int ct = blockIdx.x % 12, nt = blockIdx.x / 12;
  int c0 = ct * 32, n0 = nt * 128;
  int tid = threadIdx.x;
#pragma unroll
  for (int it = 0; it < 4; ++it) {
    int q = tid + it * 256;
    int nl = q >> 3, cg = (q & 7) * 4;
    int n = n0 + nl;
    if (n < 784) {
      s16x4 v = *(const s16x4*)(U + ((size_t)(b * 784 + n)) * 384 + c0 + cg);
      tile[cg + 0][nl] = bf2f((u16)v[0]);
      tile[cg + 1][nl] = bf2f((u16)v[1]);
      tile[cg + 2][nl] = bf2f((u16)v[2]);
      tile[cg + 3][nl] = bf2f((u16)v[3]);
    }
  }
  __syncthreads();
#pragma unroll
  for (int it = 0; it < 4; ++it) {
    int q = tid + it * 256;
    int c = q >> 5, nf = (q & 31) * 4;
    int n = n0 + nf;
    if (n + 3 < 784) {
      size_t o = ((size_t)(b * 384 + c0 + c)) * 784 + n;
      float4 xv = *(const float4*)(x + o);
      float4 r;
      r.x = xv.x + tile[c][nf + 0];
      r.y = xv.y + tile[c][nf + 1];
      r.z = xv.z + tile[c][nf + 2];
      r.w = xv.w + tile[c][nf + 3];
      *(float4*)(out + o) = r;
    }
  }
}

extern "C" void kernel_launch(void* const* d_in, const int* in_sizes, int n_in,
                              void* d_out, int out_size, void* d_ws,
                              size_t ws_size, hipStream_t stream) {
  const float* x = (const float*)d_in[0];
  const int* idx1 = (const int*)d_in[1];
  const int* idx2 = (const int*)d_in[2];
  const float* dww = (const float*)d_in[3];
  const float* dwb = (const float*)d_in[4];
  const float* nw = (const float*)d_in[5];
  const float* nb = (const float*)d_in[6];
  const float* w1 = (const float*)d_in[7];
  const float* b1 = (const float*)d_in[8];
  const float* w2 = (const float*)d_in[9];
  const float* b2 = (const float*)d_in[10];
  const float* gamma = (const float*)d_in[11];
  const float* fnw = (const float*)d_in[12];
  const float* fnb = (const float*)d_in[13];
  const float* fpw = (const float*)d_in[14];
  const float* fpb = (const float*)d_in[15];
  const float* fpg = (const float*)d_in[16];

  char* ws = (char*)d_ws;
  u16* t = (u16*)(ws);                     //  77,070,336 B (100352x384 bf16)
  u8* A1f = (u8*)(ws + 77070336);          //  19,267,584 B (50176x384 fp8)
  u8* A2f = (u8*)(ws + 96337920);          //  19,267,584 B (50176x384 fp8)
  u16* U = (u16*)(ws + 115605504);         //  77,070,336 B (100352x384 bf16)
  u8* w1p8 = (u8*)(ws + 192675840);        //     589,824 B
  u8* w2p8 = (u8*)(ws + 193265664);        //     589,824 B
  u8* fpw8 = (u8*)(ws + 193855488);        //     147,456 B
  int* rm1 = (int*)(ws + 194002944);       //     200,704 B
  int* rm2 = (int*)(ws + 194203648);       //     200,704 B
  (void)ws_size; (void)in_sizes; (void)n_in; (void)out_size;

  pack_kernel<<<1024, 256, 0, stream>>>(w1, w2, fpw, idx1, idx2, w1p8, w2p8,
                                        fpw8, rm1, rm2);
  dwconv_kernel<<<dim3(48, 128), 256, 0, stream>>>(x, dww, dwb, t);
  gatherln_kernel<<<25088, 256, 0, stream>>>(t, idx1, idx2, nw, nb, fnw, fnb,
                                             A1f, A2f);
  fused_mlp_kernel<<<1568, 256, 0, stream>>>(A1f, w1p8, w2p8, b1, b2, gamma,
                                             rm1, U);
  gemm5_kernel<<<1568, 256, 0, stream>>>(A2f, fpw8, fpb, fpg, rm2, U);
  unscatter_add_kernel<<<dim3(84, 128), 256, 0, stream>>>(U, x,
                                                          (float*)d_out);
}

// Round 22
// 387.557 us; speedup vs baseline: 1.2707x; 1.0162x over previous
//
#include <hip/hip_runtime.h>
#include <hip/hip_fp8.h>
#include <math.h>

typedef unsigned short u16;
typedef unsigned char u8;
typedef short s16x8 __attribute__((ext_vector_type(8)));
typedef short s16x4 __attribute__((ext_vector_type(4)));
typedef unsigned int u32x4 __attribute__((ext_vector_type(4)));
typedef unsigned int u32x2 __attribute__((ext_vector_type(2)));
typedef float f32x4 __attribute__((ext_vector_type(4)));
typedef unsigned short u16x2 __attribute__((ext_vector_type(2)));

__device__ __forceinline__ float bf2f(u16 u) {
  unsigned x = ((unsigned)u) << 16;
  return __builtin_bit_cast(float, x);
}
__device__ __forceinline__ u16 f2bf(float f) {
  unsigned x = __builtin_bit_cast(unsigned, f);
  unsigned r = (x + 0x7FFFu + ((x >> 16) & 1u)) >> 16;
  return (u16)r;
}
__device__ __forceinline__ u8 f2e4(float f) {
  __hip_fp8_e4m3 q(f);
  return (u8)q.__x;
}
// packed f32x2 -> 2 fp8 bytes (hardware v_cvt_pk_fp8_f32 when available)
__device__ __forceinline__ unsigned cvt2e4(float a, float b) {
#if __has_builtin(__builtin_amdgcn_cvt_pk_fp8_f32)
  return (unsigned)__builtin_amdgcn_cvt_pk_fp8_f32(a, b, 0, false) & 0xFFFFu;
#else
  return (unsigned)f2e4(a) | ((unsigned)f2e4(b) << 8);
#endif
}

// ---- fp8 MFMA: builtin operand type is 'long' (i64) on gfx950 ----
__device__ __forceinline__ f32x4 mfma8(long a, long b, f32x4 c) {
  return __builtin_amdgcn_mfma_f32_16x16x32_fp8_fp8(a, b, c, 0, 0, 0);
}

// ---- in-block gather+LayerNorm: 32 t-rows -> fp8 octet layout in Alds ----
// 256 thr: row = tid>>3 (0..31), seg = tid&7 (48 values each, 6 k-octets).
// 8-lane-group shfl reduce for mean/var (lanes of one row are contiguous).
__device__ __forceinline__ void stage_ln(
    const u16* __restrict__ t, const int* __restrict__ rm, int m_base,
    const float* __restrict__ nw, const float* __restrict__ nb, u8* Alds,
    int tid) {
  int row = tid >> 3, seg = tid & 7;
  const u16* src = t + (size_t)rm[m_base + row] * 384 + seg * 48;
  u32x4 raw[6];
#pragma unroll
  for (int o = 0; o < 6; ++o) raw[o] = *(const u32x4*)(src + o * 8);
  float s = 0.f, q = 0.f;
#pragma unroll
  for (int o = 0; o < 6; ++o)
#pragma unroll
    for (int w = 0; w < 4; ++w) {
      unsigned d = raw[o][w];
      float lo = bf2f((u16)(d & 0xFFFFu));
      float hi = bf2f((u16)(d >> 16));
      s += lo + hi;
      q += lo * lo + hi * hi;
    }
#pragma unroll
  for (int off = 1; off <= 4; off <<= 1) {
    s += __shfl_xor(s, off);
    q += __shfl_xor(q, off);
  }
  float mu = s * (1.f / 384.f);
  float var = q * (1.f / 384.f) - mu * mu;
  float rs = rsqrtf(var + 1e-6f);
#pragma unroll
  for (int o = 0; o < 6; ++o) {
    int k0 = seg * 48 + o * 8;
    float4 w0 = *(const float4*)(nw + k0);
    float4 w1 = *(const float4*)(nw + k0 + 4);
    float4 c0 = *(const float4*)(nb + k0);
    float4 c1 = *(const float4*)(nb + k0 + 4);
    unsigned d0 = raw[o][0], d1 = raw[o][1], d2 = raw[o][2], d3 = raw[o][3];
    float g0 = (bf2f((u16)(d0 & 0xFFFFu)) - mu) * rs * w0.x + c0.x;
    float g1 = (bf2f((u16)(d0 >> 16)) - mu) * rs * w0.y + c0.y;
    float g2 = (bf2f((u16)(d1 & 0xFFFFu)) - mu) * rs * w0.z + c0.z;
    float g3 = (bf2f((u16)(d1 >> 16)) - mu) * rs * w0.w + c0.w;
    float g4 = (bf2f((u16)(d2 & 0xFFFFu)) - mu) * rs * w1.x + c1.x;
    float g5 = (bf2f((u16)(d2 >> 16)) - mu) * rs * w1.y + c1.y;
    float g6 = (bf2f((u16)(d3 & 0xFFFFu)) - mu) * rs * w1.z + c1.z;
    float g7 = (bf2f((u16)(d3 >> 16)) - mu) * rs * w1.w + c1.w;
    u32x2 pk;
    pk[0] = cvt2e4(g0, g1) | (cvt2e4(g2, g3) << 16);
    pk[1] = cvt2e4(g4, g5) | (cvt2e4(g6, g7) << 16);
    *(u32x2*)&Alds[((seg * 6 + o) * 32 + row) * 8] = pk;
  }
}

// ---------------- K0: pack weights (W1,W2,fp_w -> fp8x64 octets), rowmaps ----
__global__ __launch_bounds__(256) void pack_kernel(
    const float* __restrict__ w1, const float* __restrict__ w2,
    const float* __restrict__ fpw, const int* __restrict__ idx1,
    const int* __restrict__ idx2, u8* __restrict__ w1p8, u8* __restrict__ w2p8,
    u8* __restrict__ fpw8, int* __restrict__ rm1, int* __restrict__ rm2) {
  const int T1 = 589824;           // w1 (384x1536)
  const int T2 = T1 + 589824;      // w2 (1536x384)
  const int T3 = T2 + 147456;      // fp_w (384x384)
  const int T4 = T3 + 50176;       // rowmap1
  const int T5 = T4 + 50176;       // rowmap2
  int stride = gridDim.x * 256;
  for (int i = blockIdx.x * 256 + threadIdx.x; i < T5; i += stride) {
    if (i < T1) {
      int k = i / 1536, n = i - k * 1536;
      w1p8[((size_t)(k >> 3) * 1536 + n) * 8 + (k & 7)] = f2e4(w1[i] * 64.f);
    } else if (i < T2) {
      int t = i - T1;
      int k = t / 384, n = t - k * 384;
      w2p8[((size_t)(k >> 3) * 384 + n) * 8 + (k & 7)] = f2e4(w2[t] * 64.f);
    } else if (i < T3) {
      int t = i - T2;
      int k = t / 384, n = t - k * 384;
      fpw8[((size_t)(k >> 3) * 384 + n) * 8 + (k & 7)] = f2e4(fpw[t] * 64.f);
    } else if (i < T4) {
      int g = i - T3;
      rm1[g] = (g / 392) * 784 + idx1[g];
    } else {
      int g = i - T4;
      rm2[g] = (g / 392) * 784 + idx2[g];
    }
  }
}

// ---------------- K1: depthwise 7x7 conv + bias -> t (B,N,C) bf16 ----------------
__global__ __launch_bounds__(256) void dwconv_kernel(
    const float* __restrict__ x, const float* __restrict__ dww,
    const float* __restrict__ dwb, u16* __restrict__ t) {
  __shared__ __align__(16) u16 plane[8 * 34 * 40];  // 21760 B
  int tid = threadIdx.x;
  int b = blockIdx.y, c0 = blockIdx.x * 8;
  int ch = tid & 7, row = tid >> 3;
  int c = c0 + ch;

  float wg[49];
#pragma unroll
  for (int k2 = 0; k2 < 49; ++k2) wg[k2] = dww[c * 49 + k2];
  float bias = dwb[c];

  for (int q = tid; q < 1360; q += 256) {
    s16x8 z = {0, 0, 0, 0, 0, 0, 0, 0};
    *(s16x8*)(&plane[q * 8]) = z;
  }
  __syncthreads();
  for (int q = tid; q < 1568; q += 256) {
    int cc = q / 196, seg = q - cc * 196;
    int i = seg / 7, j4 = seg - i * 7;
    const float4 v = *(const float4*)(x + ((size_t)(b * 384 + c0 + cc)) * 784 +
                                      i * 28 + j4 * 4);
    s16x4 p;
    p[0] = (short)f2bf(v.x);
    p[1] = (short)f2bf(v.y);
    p[2] = (short)f2bf(v.z);
    p[3] = (short)f2bf(v.w);
    *(s16x4*)(&plane[cc * 1360 + (3 + i) * 40 + 4 + j4 * 4]) = p;
  }
  __syncthreads();

  if (row < 28) {
    size_t obase = ((size_t)(b * 784 + row * 28)) * 384 + c;
#pragma unroll
    for (int ck = 0; ck < 4; ++ck) {
      float acc[8];
#pragma unroll
      for (int o = 0; o < 8; ++o) acc[o] = bias;
#pragma unroll
      for (int di = 0; di < 7; ++di) {
        const u16* base2 = &plane[ch * 1360 + (row + di) * 40 + ck * 8];
        u32x4 ga = *(const u32x4*)(base2);
        u32x4 gb = *(const u32x4*)(base2 + 8);
        unsigned dw[8] = {ga[0], ga[1], ga[2], ga[3],
                          gb[0], gb[1], gb[2], gb[3]};
        float v[16];
#pragma unroll
        for (int tt = 0; tt < 16; ++tt) {
          unsigned d = dw[tt >> 1];
          v[tt] = (tt & 1) ? __builtin_bit_cast(float, d & 0xFFFF0000u)
                           : __builtin_bit_cast(float, d << 16);
        }
#pragma unroll
        for (int o = 0; o < 8; ++o)
#pragma unroll
          for (int dj = 0; dj < 7; ++dj)
            acc[o] += v[o + dj + 1] * wg[di * 7 + dj];
      }
      int lim = (ck == 3) ? 4 : 8;
#pragma unroll
      for (int o = 0; o < 8; ++o)
        if (o < lim) t[obase + (size_t)(ck * 8 + o) * 384] = f2bf(acc[o]);
    }
  }
}

// ---------------- K3+K4 FUSED (fp8): U[rm1] = (gelu(LN(t[rm1])@W1+b1)@W2+b2)*gamma
// BM=32, 256 thr (4 waves). In-block gather+LN staging (no gatherln kernel).
// Hard-sigmoid gelu. fp8 e4m3 datapath (W pre-scaled x64).
__global__ __launch_bounds__(256, 4) void fused_mlp_kernel(
    const u16* __restrict__ t, const int* __restrict__ rm,
    const float* __restrict__ nw, const float* __restrict__ nb,
    const u8* __restrict__ w1p8, const u8* __restrict__ w2p8,
    const float* __restrict__ b1, const float* __restrict__ b2,
    const float* __restrict__ gamma, u16* __restrict__ U) {
  __shared__ __align__(16) u8 Alds[48 * 32 * 8];     // 12288 B
  __shared__ __align__(16) u8 Plds[2][24 * 32 * 8];  // 2 x 6144 B
  int tid = threadIdx.x;
  int wid = tid >> 6, lane = tid & 63;
  int kgl = lane >> 4, rl = lane & 15;
  int cl = lane & 15, rg = (lane >> 4) * 4;
  int m_base = blockIdx.x * 32;

  stage_ln(t, rm, m_base, nw, nb, Alds, tid);

  const f32x4 vzero = {0.f, 0.f, 0.f, 0.f};
  f32x4 accB[2][6];
#pragma unroll
  for (int i = 0; i < 2; ++i)
#pragma unroll
    for (int j = 0; j < 6; ++j) accB[i][j] = vzero;

  __syncthreads();

#pragma unroll 1
  for (int c = 0; c < 8; ++c) {
    u8* Pl = Plds[c & 1];
    // ---- phase A: accA = A(32x384) @ W1[:, c*192 + wid*48 .. +48] ----
    f32x4 accA[2][3];
#pragma unroll
    for (int i = 0; i < 2; ++i)
#pragma unroll
      for (int j = 0; j < 3; ++j) accA[i][j] = vzero;
#pragma unroll
    for (int ks = 0; ks < 12; ++ks) {
      long af[2], bw[3];
#pragma unroll
      for (int i = 0; i < 2; ++i)
        af[i] = *(const long*)&Alds[((ks * 4 + kgl) * 32 + i * 16 + rl) * 8];
#pragma unroll
      for (int j = 0; j < 3; ++j) {
        int col = c * 192 + wid * 48 + j * 16 + rl;
        bw[j] = *(const long*)(w1p8 + ((size_t)(ks * 4 + kgl) * 1536 + col) * 8);
      }
      __builtin_amdgcn_s_setprio(1);
#pragma unroll
      for (int i = 0; i < 2; ++i)
#pragma unroll
        for (int j = 0; j < 3; ++j)
          accA[i][j] = mfma8(af[i], bw[j], accA[i][j]);
      __builtin_amdgcn_s_setprio(0);
    }
    // bias + hard-sigmoid gelu -> Pl fp8 (unscale W1's x64)
    float b1v[3];
#pragma unroll
    for (int j = 0; j < 3; ++j) b1v[j] = b1[c * 192 + wid * 48 + j * 16 + cl];
#pragma unroll
    for (int i = 0; i < 2; ++i)
#pragma unroll
      for (int j = 0; j < 3; ++j) {
        int col = wid * 48 + j * 16 + cl;
        float g2[4];
#pragma unroll
        for (int reg = 0; reg < 4; ++reg) {
          float v = accA[i][j][reg] * 0.015625f + b1v[j];
          g2[reg] = v * fminf(fmaxf(0.4255f * v + 0.5f, 0.f), 1.f);
        }
        unsigned p01 = cvt2e4(g2[0], g2[1]);
        unsigned p23 = cvt2e4(g2[2], g2[3]);
        int base = ((col >> 3) * 32 + i * 16 + rg) * 8 + (col & 7);
        Pl[base] = (u8)p01;
        Pl[base + 8] = (u8)(p01 >> 8);
        Pl[base + 16] = (u8)p23;
        Pl[base + 24] = (u8)(p23 >> 8);
      }
    __syncthreads();
    // ---- phase B: accB += P(32x192) @ W2[c*192.., wid*96 .. +96] ----
#pragma unroll
    for (int ks = 0; ks < 6; ++ks) {
      long ap[2], bw2[6];
#pragma unroll
      for (int i = 0; i < 2; ++i)
        ap[i] = *(const long*)&Pl[((ks * 4 + kgl) * 32 + i * 16 + rl) * 8];
#pragma unroll
      for (int j = 0; j < 6; ++j) {
        int col = wid * 96 + j * 16 + rl;
        int ko2 = c * 24 + ks * 4 + kgl;
        bw2[j] = *(const long*)(w2p8 + ((size_t)ko2 * 384 + col) * 8);
      }
      __builtin_amdgcn_s_setprio(1);
#pragma unroll
      for (int i = 0; i < 2; ++i)
#pragma unroll
        for (int j = 0; j < 6; ++j)
          accB[i][j] = mfma8(ap[i], bw2[j], accB[i][j]);
      __builtin_amdgcn_s_setprio(0);
    }
    // no second barrier: next chunk writes the OTHER P buffer
  }

  // epilogue: U[rm[m]*384 + col] = bf16((accB/64 + b2[col]) * gamma[col])
#pragma unroll
  for (int i = 0; i < 2; ++i) {
#pragma unroll
    for (int reg = 0; reg < 4; ++reg) {
      int m = m_base + i * 16 + rg + reg;
      size_t rowoff = (size_t)rm[m] * 384;
#pragma unroll
      for (int j = 0; j < 6; ++j) {
        int col = wid * 96 + j * 16 + cl;
        float v = (accB[i][j][reg] * 0.015625f + b2[col]) * gamma[col];
        U[rowoff + col] = f2bf(v);
      }
    }
  }
}

// ---------------- K5 (fp8): U[rm2] = (LN(t[rm2]) @ fp_w + fp_b) * fp_gamma ----
__global__ __launch_bounds__(256, 4) void gemm5_kernel(
    const u16* __restrict__ t, const int* __restrict__ rm,
    const float* __restrict__ nw, const float* __restrict__ nb,
    const u8* __restrict__ wp8, const float* __restrict__ bias,
    const float* __restrict__ scale, u16* __restrict__ U) {
  __shared__ __align__(16) u8 Alds[48 * 32 * 8];  // 12288 B
  int tid = threadIdx.x;
  int wid = tid >> 6, lane = tid & 63;
  int kgl = lane >> 4, rl = lane & 15;
  int cl = lane & 15, rg = (lane >> 4) * 4;
  int m_base = blockIdx.x * 32;

  stage_ln(t, rm, m_base, nw, nb, Alds, tid);

  const f32x4 vzero = {0.f, 0.f, 0.f, 0.f};
  f32x4 acc[2][6];
#pragma unroll
  for (int i = 0; i < 2; ++i)
#pragma unroll
    for (int j = 0; j < 6; ++j) acc[i][j] = vzero;

  __syncthreads();

#pragma unroll
  for (int ks = 0; ks < 12; ++ks) {
    long af[2], bw[6];
#pragma unroll
    for (int i = 0; i < 2; ++i)
      af[i] = *(const long*)&Alds[((ks * 4 + kgl) * 32 + i * 16 + rl) * 8];
#pragma unroll
    for (int j = 0; j < 6; ++j) {
      int col = wid * 96 + j * 16 + rl;
      bw[j] = *(const long*)(wp8 + ((size_t)(ks * 4 + kgl) * 384 + col) * 8);
    }
    __builtin_amdgcn_s_setprio(1);
#pragma unroll
    for (int i = 0; i < 2; ++i)
#pragma unroll
      for (int j = 0; j < 6; ++j)
        acc[i][j] = mfma8(af[i], bw[j], acc[i][j]);
    __builtin_amdgcn_s_setprio(0);
  }

#pragma unroll
  for (int i = 0; i < 2; ++i) {
#pragma unroll
    for (int reg = 0; reg < 4; ++reg) {
      int m = m_base + i * 16 + rg + reg;
      size_t rowoff = (size_t)rm[m] * 384;
#pragma unroll
      for (int j = 0; j < 6; ++j) {
        int col = wid * 96 + j * 16 + cl;
        float v = (acc[i][j][reg] * 0.015625f + bias[col]) * scale[col];
        U[rowoff + col] = f2bf(v);
      }
    }
  }
}

// ---------------- K6: un-transpose (B,N,C)->(B,C,N) + residual add ----------------
__global__ __launch_bounds__(256) void unscatter_add_kernel(
    const u16* __restrict__ U, const float* __restrict__ x,
    float* __restrict__ out) {
  __shared__ float tile[32][129];
  int b = blockIdx.y;
  int ct = blockIdx.x % 12, nt = blockIdx.x / 12;
  int c0 = ct * 32, n0 = nt * 128;
  int tid = threadIdx.x;
#pragma unroll
  for (int it = 0; it < 4; ++it) {
    int q = tid + it * 256;
    int nl = q >> 3, cg = (q & 7) * 4;
    int n = n0 + nl;
    if (n < 784) {
      s16x4 v = *(const s16x4*)(U + ((size_t)(b * 784 + n)) * 384 + c0 + cg);
      tile[cg + 0][nl] = bf2f((u16)v[0]);
      tile[cg + 1][nl] = bf2f((u16)v[1]);
      tile[cg + 2][nl] = bf2f((u16)v[2]);
      tile[cg + 3][nl] = bf2f((u16)v[3]);
    }
  }
  __syncthreads();
#pragma unroll
  for (int it = 0; it < 4; ++it) {
    int q = tid + it * 256;
    int c = q >> 5, nf = (q & 31) * 4;
    int n = n0 + nf;
    if (n + 3 < 784) {
      size_t o = ((size_t)(b * 384 + c0 + c)) * 784 + n;
      float4 xv = *(const float4*)(x + o);
      float4 r;
      r.x = xv.x + tile[c][nf + 0];
      r.y = xv.y + tile[c][nf + 1];
      r.z = xv.z + tile[c][nf + 2];
      r.w = xv.w + tile[c][nf + 3];
      *(float4*)(out + o) = r;
    }
  }
}

extern "C" void kernel_launch(void* const* d_in, const int* in_sizes, int n_in,
                              void* d_out, int out_size, void* d_ws,
                              size_t ws_size, hipStream_t stream) {
  const float* x = (const float*)d_in[0];
  const int* idx1 = (const int*)d_in[1];
  const int* idx2 = (const int*)d_in[2];
  const float* dww = (const float*)d_in[3];
  const float* dwb = (const float*)d_in[4];
  const float* nw = (const float*)d_in[5];
  const float* nb = (const float*)d_in[6];
  const float* w1 = (const float*)d_in[7];
  const float* b1 = (const float*)d_in[8];
  const float* w2 = (const float*)d_in[9];
  const float* b2 = (const float*)d_in[10];
  const float* gamma = (const float*)d_in[11];
  const float* fnw = (const float*)d_in[12];
  const float* fnb = (const float*)d_in[13];
  const float* fpw = (const float*)d_in[14];
  const float* fpb = (const float*)d_in[15];
  const float* fpg = (const float*)d_in[16];

  char* ws = (char*)d_ws;
  u16* t = (u16*)(ws);                     //  77,070,336 B (100352x384 bf16)
  u16* U = (u16*)(ws + 77070336);          //  77,070,336 B (100352x384 bf16)
  u8* w1p8 = (u8*)(ws + 154140672);        //     589,824 B
  u8* w2p8 = (u8*)(ws + 154730496);        //     589,824 B
  u8* fpw8 = (u8*)(ws + 155320320);        //     147,456 B
  int* rm1 = (int*)(ws + 155467776);       //     200,704 B
  int* rm2 = (int*)(ws + 155668480);       //     200,704 B
  (void)ws_size; (void)in_sizes; (void)n_in; (void)out_size;

  pack_kernel<<<1024, 256, 0, stream>>>(w1, w2, fpw, idx1, idx2, w1p8, w2p8,
                                        fpw8, rm1, rm2);
  dwconv_kernel<<<dim3(48, 128), 256, 0, stream>>>(x, dww, dwb, t);
  fused_mlp_kernel<<<1568, 256, 0, stream>>>(t, rm1, nw, nb, w1p8, w2p8, b1,
                                             b2, gamma, U);
  gemm5_kernel<<<1568, 256, 0, stream>>>(t, rm2, fnw, fnb, fpw8, fpb, fpg, U);
  unscatter_add_kernel<<<dim3(84, 128), 256, 0, stream>>>(U, x,
                                                          (float*)d_out);
}

// Round 23
// 350.711 us; speedup vs baseline: 1.4043x; 1.1051x over previous
//
#include <hip/hip_runtime.h>
#include <hip/hip_fp8.h>
#include <math.h>

typedef unsigned short u16;
typedef unsigned char u8;
typedef short s16x8 __attribute__((ext_vector_type(8)));
typedef short s16x4 __attribute__((ext_vector_type(4)));
typedef unsigned int u32x4 __attribute__((ext_vector_type(4)));
typedef unsigned int u32x2 __attribute__((ext_vector_type(2)));
typedef float f32x4 __attribute__((ext_vector_type(4)));
typedef unsigned short u16x2 __attribute__((ext_vector_type(2)));

__device__ __forceinline__ float bf2f(u16 u) {
  unsigned x = ((unsigned)u) << 16;
  return __builtin_bit_cast(float, x);
}
__device__ __forceinline__ u16 f2bf(float f) {
  unsigned x = __builtin_bit_cast(unsigned, f);
  unsigned r = (x + 0x7FFFu + ((x >> 16) & 1u)) >> 16;
  return (u16)r;
}
__device__ __forceinline__ u8 f2e4(float f) {
  __hip_fp8_e4m3 q(f);
  return (u8)q.__x;
}
__device__ __forceinline__ unsigned cvt2e4(float a, float b) {
#if __has_builtin(__builtin_amdgcn_cvt_pk_fp8_f32)
  return (unsigned)__builtin_amdgcn_cvt_pk_fp8_f32(a, b, 0, false) & 0xFFFFu;
#else
  return (unsigned)f2e4(a) | ((unsigned)f2e4(b) << 8);
#endif
}

// ---- fp8 MFMA: builtin operand type is 'long' (i64) on gfx950 ----
__device__ __forceinline__ f32x4 mfma8(long a, long b, f32x4 c) {
  return __builtin_amdgcn_mfma_f32_16x16x32_fp8_fp8(a, b, c, 0, 0, 0);
}

// ---- in-block gather+LayerNorm: 32 t-rows -> fp8 octet layout in Alds ----
__device__ __forceinline__ void stage_ln(
    const u16* __restrict__ t, const int* __restrict__ rm, int m_base,
    const float* __restrict__ nw, const float* __restrict__ nb, u8* Alds,
    int tid) {
  int row = tid >> 3, seg = tid & 7;
  const u16* src = t + (size_t)rm[m_base + row] * 384 + seg * 48;
  u32x4 raw[6];
#pragma unroll
  for (int o = 0; o < 6; ++o) raw[o] = *(const u32x4*)(src + o * 8);
  float s = 0.f, q = 0.f;
#pragma unroll
  for (int o = 0; o < 6; ++o)
#pragma unroll
    for (int w = 0; w < 4; ++w) {
      unsigned d = raw[o][w];
      float lo = bf2f((u16)(d & 0xFFFFu));
      float hi = bf2f((u16)(d >> 16));
      s += lo + hi;
      q += lo * lo + hi * hi;
    }
#pragma unroll
  for (int off = 1; off <= 4; off <<= 1) {
    s += __shfl_xor(s, off);
    q += __shfl_xor(q, off);
  }
  float mu = s * (1.f / 384.f);
  float var = q * (1.f / 384.f) - mu * mu;
  float rs = rsqrtf(var + 1e-6f);
#pragma unroll
  for (int o = 0; o < 6; ++o) {
    int k0 = seg * 48 + o * 8;
    float4 w0 = *(const float4*)(nw + k0);
    float4 w1 = *(const float4*)(nw + k0 + 4);
    float4 c0 = *(const float4*)(nb + k0);
    float4 c1 = *(const float4*)(nb + k0 + 4);
    unsigned d0 = raw[o][0], d1 = raw[o][1], d2 = raw[o][2], d3 = raw[o][3];
    float g0 = (bf2f((u16)(d0 & 0xFFFFu)) - mu) * rs * w0.x + c0.x;
    float g1 = (bf2f((u16)(d0 >> 16)) - mu) * rs * w0.y + c0.y;
    float g2 = (bf2f((u16)(d1 & 0xFFFFu)) - mu) * rs * w0.z + c0.z;
    float g3 = (bf2f((u16)(d1 >> 16)) - mu) * rs * w0.w + c0.w;
    float g4 = (bf2f((u16)(d2 & 0xFFFFu)) - mu) * rs * w1.x + c1.x;
    float g5 = (bf2f((u16)(d2 >> 16)) - mu) * rs * w1.y + c1.y;
    float g6 = (bf2f((u16)(d3 & 0xFFFFu)) - mu) * rs * w1.z + c1.z;
    float g7 = (bf2f((u16)(d3 >> 16)) - mu) * rs * w1.w + c1.w;
    u32x2 pk;
    pk[0] = cvt2e4(g0, g1) | (cvt2e4(g2, g3) << 16);
    pk[1] = cvt2e4(g4, g5) | (cvt2e4(g6, g7) << 16);
    *(u32x2*)&Alds[((seg * 6 + o) * 32 + row) * 8] = pk;
  }
}

// ---------------- PREP (merged): dwconv (blocks 0..6143) || pack (6144..7167) ----
__global__ __launch_bounds__(256) void prep_kernel(
    const float* __restrict__ x, const float* __restrict__ dww,
    const float* __restrict__ dwb, u16* __restrict__ t,
    const float* __restrict__ w1, const float* __restrict__ w2,
    const float* __restrict__ fpw, const int* __restrict__ idx1,
    const int* __restrict__ idx2, u8* __restrict__ w1p8, u8* __restrict__ w2p8,
    u8* __restrict__ fpw8, int* __restrict__ rm1, int* __restrict__ rm2) {
  __shared__ __align__(16) u16 plane[8 * 34 * 40];  // 21760 B
  int tid = threadIdx.x;
  int bid = blockIdx.x;
  if (bid >= 6144) {
    // ---- pack path (1024 blocks, grid-stride with fixed stride) ----
    const int T1 = 589824, T2 = T1 + 589824, T3 = T2 + 147456,
              T4 = T3 + 50176, T5 = T4 + 50176;
    for (int i = (bid - 6144) * 256 + tid; i < T5; i += 1024 * 256) {
      if (i < T1) {
        int k = i / 1536, n = i - k * 1536;
        w1p8[((size_t)(k >> 3) * 1536 + n) * 8 + (k & 7)] = f2e4(w1[i] * 64.f);
      } else if (i < T2) {
        int v = i - T1;
        int k = v / 384, n = v - k * 384;
        w2p8[((size_t)(k >> 3) * 384 + n) * 8 + (k & 7)] = f2e4(w2[v] * 64.f);
      } else if (i < T3) {
        int v = i - T2;
        int k = v / 384, n = v - k * 384;
        fpw8[((size_t)(k >> 3) * 384 + n) * 8 + (k & 7)] = f2e4(fpw[v] * 64.f);
      } else if (i < T4) {
        int g = i - T3;
        rm1[g] = (g / 392) * 784 + idx1[g];
      } else {
        int g = i - T4;
        rm2[g] = (g / 392) * 784 + idx2[g];
      }
    }
    return;
  }
  // ---- dwconv path ----
  int b = bid / 48, c0 = (bid - b * 48) * 8;
  int ch = tid & 7, row = tid >> 3;
  int c = c0 + ch;

  float wg[49];
#pragma unroll
  for (int k2 = 0; k2 < 49; ++k2) wg[k2] = dww[c * 49 + k2];
  float bias = dwb[c];

  for (int q = tid; q < 1360; q += 256) {
    s16x8 z = {0, 0, 0, 0, 0, 0, 0, 0};
    *(s16x8*)(&plane[q * 8]) = z;
  }
  __syncthreads();
  for (int q = tid; q < 1568; q += 256) {
    int cc = q / 196, seg = q - cc * 196;
    int i = seg / 7, j4 = seg - i * 7;
    const float4 v = *(const float4*)(x + ((size_t)(b * 384 + c0 + cc)) * 784 +
                                      i * 28 + j4 * 4);
    s16x4 p;
    p[0] = (short)f2bf(v.x);
    p[1] = (short)f2bf(v.y);
    p[2] = (short)f2bf(v.z);
    p[3] = (short)f2bf(v.w);
    *(s16x4*)(&plane[cc * 1360 + (3 + i) * 40 + 4 + j4 * 4]) = p;
  }
  __syncthreads();

  if (row < 28) {
    size_t obase = ((size_t)(b * 784 + row * 28)) * 384 + c;
#pragma unroll
    for (int ck = 0; ck < 4; ++ck) {
      float acc[8];
#pragma unroll
      for (int o = 0; o < 8; ++o) acc[o] = bias;
#pragma unroll
      for (int di = 0; di < 7; ++di) {
        const u16* base2 = &plane[ch * 1360 + (row + di) * 40 + ck * 8];
        u32x4 ga = *(const u32x4*)(base2);
        u32x4 gb = *(const u32x4*)(base2 + 8);
        unsigned dw[8] = {ga[0], ga[1], ga[2], ga[3],
                          gb[0], gb[1], gb[2], gb[3]};
        float v[16];
#pragma unroll
        for (int tt = 0; tt < 16; ++tt) {
          unsigned d = dw[tt >> 1];
          v[tt] = (tt & 1) ? __builtin_bit_cast(float, d & 0xFFFF0000u)
                           : __builtin_bit_cast(float, d << 16);
        }
#pragma unroll
        for (int o = 0; o < 8; ++o)
#pragma unroll
          for (int dj = 0; dj < 7; ++dj)
            acc[o] += v[o + dj + 1] * wg[di * 7 + dj];
      }
      int lim = (ck == 3) ? 4 : 8;
#pragma unroll
      for (int o = 0; o < 8; ++o)
        if (o < lim) t[obase + (size_t)(ck * 8 + o) * 384] = f2bf(acc[o]);
    }
  }
}

// ---------------- MLP (merged): fused MLP (blocks 0..1567) || gemm5 (1568..3135)
// Both paths: BM=32, 256 thr, in-block gather+LN staging, fp8 MFMA datapath.
__global__ __launch_bounds__(256, 4) void mlp_kernel(
    const u16* __restrict__ t, const int* __restrict__ rm1,
    const int* __restrict__ rm2, const float* __restrict__ nw,
    const float* __restrict__ nb, const float* __restrict__ fnw,
    const float* __restrict__ fnb, const u8* __restrict__ w1p8,
    const u8* __restrict__ w2p8, const u8* __restrict__ fpw8,
    const float* __restrict__ b1, const float* __restrict__ b2,
    const float* __restrict__ gamma, const float* __restrict__ fpb,
    const float* __restrict__ fpg, u16* __restrict__ U) {
  __shared__ __align__(16) u8 Alds[48 * 32 * 8];     // 12288 B
  __shared__ __align__(16) u8 Plds[2][24 * 32 * 8];  // 2 x 6144 B
  int tid = threadIdx.x;
  int wid = tid >> 6, lane = tid & 63;
  int kgl = lane >> 4, rl = lane & 15;
  int cl = lane & 15, rg = (lane >> 4) * 4;
  int bid = blockIdx.x;
  const f32x4 vzero = {0.f, 0.f, 0.f, 0.f};

  if (bid >= 1568) {
    // ---- gemm5 path: U[rm2] = (LN(t[rm2]) @ fp_w + fp_b) * fp_gamma ----
    int m_base = (bid - 1568) * 32;
    stage_ln(t, rm2, m_base, fnw, fnb, Alds, tid);
    f32x4 acc[2][6];
#pragma unroll
    for (int i = 0; i < 2; ++i)
#pragma unroll
      for (int j = 0; j < 6; ++j) acc[i][j] = vzero;
    __syncthreads();
#pragma unroll
    for (int ks = 0; ks < 12; ++ks) {
      long af[2], bw[6];
#pragma unroll
      for (int i = 0; i < 2; ++i)
        af[i] = *(const long*)&Alds[((ks * 4 + kgl) * 32 + i * 16 + rl) * 8];
#pragma unroll
      for (int j = 0; j < 6; ++j) {
        int col = wid * 96 + j * 16 + rl;
        bw[j] = *(const long*)(fpw8 + ((size_t)(ks * 4 + kgl) * 384 + col) * 8);
      }
      __builtin_amdgcn_s_setprio(1);
#pragma unroll
      for (int i = 0; i < 2; ++i)
#pragma unroll
        for (int j = 0; j < 6; ++j)
          acc[i][j] = mfma8(af[i], bw[j], acc[i][j]);
      __builtin_amdgcn_s_setprio(0);
    }
#pragma unroll
    for (int i = 0; i < 2; ++i) {
#pragma unroll
      for (int reg = 0; reg < 4; ++reg) {
        int m = m_base + i * 16 + rg + reg;
        size_t rowoff = (size_t)rm2[m] * 384;
#pragma unroll
        for (int j = 0; j < 6; ++j) {
          int col = wid * 96 + j * 16 + cl;
          float v = (acc[i][j][reg] * 0.015625f + fpb[col]) * fpg[col];
          U[rowoff + col] = f2bf(v);
        }
      }
    }
    return;
  }

  // ---- fused MLP path: U[rm1] = (gelu(LN(t[rm1])@W1+b1)@W2 + b2)*gamma ----
  int m_base = bid * 32;
  stage_ln(t, rm1, m_base, nw, nb, Alds, tid);

  f32x4 accB[2][6];
#pragma unroll
  for (int i = 0; i < 2; ++i)
#pragma unroll
    for (int j = 0; j < 6; ++j) accB[i][j] = vzero;

  __syncthreads();

#pragma unroll 1
  for (int c = 0; c < 8; ++c) {
    u8* Pl = Plds[c & 1];
    f32x4 accA[2][3];
#pragma unroll
    for (int i = 0; i < 2; ++i)
#pragma unroll
      for (int j = 0; j < 3; ++j) accA[i][j] = vzero;
#pragma unroll
    for (int ks = 0; ks < 12; ++ks) {
      long af[2], bw[3];
#pragma unroll
      for (int i = 0; i < 2; ++i)
        af[i] = *(const long*)&Alds[((ks * 4 + kgl) * 32 + i * 16 + rl) * 8];
#pragma unroll
      for (int j = 0; j < 3; ++j) {
        int col = c * 192 + wid * 48 + j * 16 + rl;
        bw[j] = *(const long*)(w1p8 + ((size_t)(ks * 4 + kgl) * 1536 + col) * 8);
      }
      __builtin_amdgcn_s_setprio(1);
#pragma unroll
      for (int i = 0; i < 2; ++i)
#pragma unroll
        for (int j = 0; j < 3; ++j)
          accA[i][j] = mfma8(af[i], bw[j], accA[i][j]);
      __builtin_amdgcn_s_setprio(0);
    }
    float b1v[3];
#pragma unroll
    for (int j = 0; j < 3; ++j) b1v[j] = b1[c * 192 + wid * 48 + j * 16 + cl];
#pragma unroll
    for (int i = 0; i < 2; ++i)
#pragma unroll
      for (int j = 0; j < 3; ++j) {
        int col = wid * 48 + j * 16 + cl;
        float g2[4];
#pragma unroll
        for (int reg = 0; reg < 4; ++reg) {
          float v = accA[i][j][reg] * 0.015625f + b1v[j];
          g2[reg] = v * fminf(fmaxf(0.4255f * v + 0.5f, 0.f), 1.f);
        }
        unsigned p01 = cvt2e4(g2[0], g2[1]);
        unsigned p23 = cvt2e4(g2[2], g2[3]);
        int base = ((col >> 3) * 32 + i * 16 + rg) * 8 + (col & 7);
        Pl[base] = (u8)p01;
        Pl[base + 8] = (u8)(p01 >> 8);
        Pl[base + 16] = (u8)p23;
        Pl[base + 24] = (u8)(p23 >> 8);
      }
    __syncthreads();
#pragma unroll
    for (int ks = 0; ks < 6; ++ks) {
      long ap[2], bw2[6];
#pragma unroll
      for (int i = 0; i < 2; ++i)
        ap[i] = *(const long*)&Pl[((ks * 4 + kgl) * 32 + i * 16 + rl) * 8];
#pragma unroll
      for (int j = 0; j < 6; ++j) {
        int col = wid * 96 + j * 16 + rl;
        int ko2 = c * 24 + ks * 4 + kgl;
        bw2[j] = *(const long*)(w2p8 + ((size_t)ko2 * 384 + col) * 8);
      }
      __builtin_amdgcn_s_setprio(1);
#pragma unroll
      for (int i = 0; i < 2; ++i)
#pragma unroll
        for (int j = 0; j < 6; ++j)
          accB[i][j] = mfma8(ap[i], bw2[j], accB[i][j]);
      __builtin_amdgcn_s_setprio(0);
    }
  }

#pragma unroll
  for (int i = 0; i < 2; ++i) {
#pragma unroll
    for (int reg = 0; reg < 4; ++reg) {
      int m = m_base + i * 16 + rg + reg;
      size_t rowoff = (size_t)rm1[m] * 384;
#pragma unroll
      for (int j = 0; j < 6; ++j) {
        int col = wid * 96 + j * 16 + cl;
        float v = (accB[i][j][reg] * 0.015625f + b2[col]) * gamma[col];
        U[rowoff + col] = f2bf(v);
      }
    }
  }
}

// ---------------- K6: un-transpose (B,N,C)->(B,C,N) + residual add ----------------
__global__ __launch_bounds__(256) void unscatter_add_kernel(
    const u16* __restrict__ U, const float* __restrict__ x,
    float* __restrict__ out) {
  __shared__ float tile[32][129];
  int b = blockIdx.y;
  int ct = blockIdx.x % 12, nt = blockIdx.x / 12;
  int c0 = ct * 32, n0 = nt * 128;
  int tid = threadIdx.x;
#pragma unroll
  for (int it = 0; it < 4; ++it) {
    int q = tid + it * 256;
    int nl = q >> 3, cg = (q & 7) * 4;
    int n = n0 + nl;
    if (n < 784) {
      s16x4 v = *(const s16x4*)(U + ((size_t)(b * 784 + n)) * 384 + c0 + cg);
      tile[cg + 0][nl] = bf2f((u16)v[0]);
      tile[cg + 1][nl] = bf2f((u16)v[1]);
      tile[cg + 2][nl] = bf2f((u16)v[2]);
      tile[cg + 3][nl] = bf2f((u16)v[3]);
    }
  }
  __syncthreads();
#pragma unroll
  for (int it = 0; it < 4; ++it) {
    int q = tid + it * 256;
    int c = q >> 5, nf = (q & 31) * 4;
    int n = n0 + nf;
    if (n + 3 < 784) {
      size_t o = ((size_t)(b * 384 + c0 + c)) * 784 + n;
      float4 xv = *(const float4*)(x + o);
      float4 r;
      r.x = xv.x + tile[c][nf + 0];
      r.y = xv.y + tile[c][nf + 1];
      r.z = xv.z + tile[c][nf + 2];
      r.w = xv.w + tile[c][nf + 3];
      *(float4*)(out + o) = r;
    }
  }
}

extern "C" void kernel_launch(void* const* d_in, const int* in_sizes, int n_in,
                              void* d_out, int out_size, void* d_ws,
                              size_t ws_size, hipStream_t stream) {
  const float* x = (const float*)d_in[0];
  const int* idx1 = (const int*)d_in[1];
  const int* idx2 = (const int*)d_in[2];
  const float* dww = (const float*)d_in[3];
  const float* dwb = (const float*)d_in[4];
  const float* nw = (const float*)d_in[5];
  const float* nb = (const float*)d_in[6];
  const float* w1 = (const float*)d_in[7];
  const float* b1 = (const float*)d_in[8];
  const float* w2 = (const float*)d_in[9];
  const float* b2 = (const float*)d_in[10];
  const float* gamma = (const float*)d_in[11];
  const float* fnw = (const float*)d_in[12];
  const float* fnb = (const float*)d_in[13];
  const float* fpw = (const float*)d_in[14];
  const float* fpb = (const float*)d_in[15];
  const float* fpg = (const float*)d_in[16];

  char* ws = (char*)d_ws;
  u16* t = (u16*)(ws);                     //  77,070,336 B (100352x384 bf16)
  u16* U = (u16*)(ws + 77070336);          //  77,070,336 B (100352x384 bf16)
  u8* w1p8 = (u8*)(ws + 154140672);        //     589,824 B
  u8* w2p8 = (u8*)(ws + 154730496);        //     589,824 B
  u8* fpw8 = (u8*)(ws + 155320320);        //     147,456 B
  int* rm1 = (int*)(ws + 155467776);       //     200,704 B
  int* rm2 = (int*)(ws + 155668480);       //     200,704 B
  (void)ws_size; (void)in_sizes; (void)n_in; (void)out_size;

  prep_kernel<<<7168, 256, 0, stream>>>(x, dww, dwb, t, w1, w2, fpw, idx1,
                                        idx2, w1p8, w2p8, fpw8, rm1, rm2);
  mlp_kernel<<<3136, 256, 0, stream>>>(t, rm1, rm2, nw, nb, fnw, fnb, w1p8,
                                       w2p8, fpw8, b1, b2, gamma, fpb, fpg, U);
  unscatter_add_kernel<<<dim3(84, 128), 256, 0, stream>>>(U, x,
                                                          (float*)d_out);
}